// Round 7
// baseline (269.070 us; speedup 1.0000x reference)
//
#include <hip/hip_runtime.h>
#include <hip/hip_bf16.h>

// Problem constants
#define NQ 8192            // B*S flattened tokens
#define DIM 64             // embed dim
#define SPLITS 16          // key-dimension split (partials merged by last block)
#define FQB 64             // queries per flash block = ONE wave
#define KEYS_PER_SPLIT (NQ / SPLITS)       // 512
#define NSTEPS (KEYS_PER_SPLIT / 32)       // 16 x 32-key steps
#define GRID_FLASH ((NQ / FQB) * SPLITS)   // 2048
#define NQB (NQ / FQB)                     // 128 qblocks (merge counters)
#define SC2 0.51012301920911057f           // (1/sqrt(8)) * log2(e), folded into qq
#define ATTSTR 68          // merge att LDS row stride in floats (2-way banks)

typedef short s8v __attribute__((ext_vector_type(8)));   // 8 x bf16 bits
typedef short s4v __attribute__((ext_vector_type(4)));   // 4 x bf16 bits
typedef float f4v __attribute__((ext_vector_type(4)));
typedef int   i4v __attribute__((ext_vector_type(4)));

__device__ __forceinline__ float b2f(short s) {
  unsigned int u = ((unsigned int)(unsigned short)s) << 16;
  return __uint_as_float(u);
}
__device__ __forceinline__ float b2f_lo(unsigned int u) {
  return __uint_as_float(u << 16);
}
__device__ __forceinline__ float b2f_hi(unsigned int u) {
  return __uint_as_float(u & 0xffff0000u);
}
__device__ __forceinline__ short f2b(float f) {
  __hip_bfloat16 h = __float2bfloat16(f);
  return *reinterpret_cast<short*>(&h);
}
__device__ __forceinline__ int pack_bf16x2(float a, float b) {
  union { __hip_bfloat162 h; int i; } u;
  u.h = __float22bfloat162_rn(make_float2(a, b));
  return u.i;
}
__device__ __forceinline__ float fast_exp2(float x) {
#if __has_builtin(__builtin_amdgcn_exp2f)
  return __builtin_amdgcn_exp2f(x);   // single v_exp_f32, no OCML call
#else
  return exp2f(x);
#endif
}
__device__ __forceinline__ float fast_rcp(float x) {
#if __has_builtin(__builtin_amdgcn_rcpf)
  return __builtin_amdgcn_rcpf(x);
#else
  return 1.f / x;
#endif
}

// ---------------- QKV projection + quantum map (fp32 in, bf16 out) ----------
// One wave per block, grid (512 token-groups x 3 mt-groups) = 1536 blocks
// (6 blocks/CU, free-running: no LDS, no barriers). Each wave reads its W
// MFMA fragments DIRECTLY from the fp32 weight matrix (L2-resident after
// first touch) and converts in-register. 8 MFMAs + cos epilogue.
// Block (0,0) also zeroes the merge counters (visible to flash at the
// kernel boundary, which is a device-scope release).
// kvT is FRAGMENT-LINEAR TILED (8192 shorts per 64-key tile: 8 K-chunks then
// 8 V-chunks of 512 = chunk*512 + lane*8 + j); V chunks bake in the K=32 PV
// key permutation.
__global__ __launch_bounds__(64) void qkv_kernel(
    const float* __restrict__ x,
    const float* __restrict__ wq, const float* __restrict__ bq,
    const float* __restrict__ wk, const float* __restrict__ bk,
    const float* __restrict__ wv, const float* __restrict__ bv,
    const float* __restrict__ theta,
    short* __restrict__ qq, short* __restrict__ kvT, int* __restrict__ cnt) {
  int lane = threadIdx.x & 63;
  int l15 = lane & 15, quad = lane >> 4;
  int tg = blockIdx.x;     // token group (16 tokens)
  int mg = blockIdx.y;     // 0 = Q, 1 = K, 2 = V
  int n = tg * 16 + l15;   // this lane's token (as C column)

  if ((tg | mg) == 0) {    // zero the merge counters for this launch
    cnt[lane] = 0;
    cnt[lane + 64] = 0;
  }

  const float* W  = (mg == 0) ? wq : (mg == 1) ? wk : wv;
  const float* Bb = (mg == 0) ? bq : (mg == 1) ? bk : bv;

  // B-frag: X[token = l15][k = quad*8 + j], two k-halves (fp32 -> bf16)
  const float* xr = x + (size_t)n * DIM + quad * 8;
  float4 x0 = *(const float4*)&xr[0];
  float4 x1 = *(const float4*)&xr[4];
  float4 x2 = *(const float4*)&xr[32];
  float4 x3 = *(const float4*)&xr[36];
  s8v xf0 = {f2b(x0.x), f2b(x0.y), f2b(x0.z), f2b(x0.w),
             f2b(x1.x), f2b(x1.y), f2b(x1.z), f2b(x1.w)};
  s8v xf1 = {f2b(x2.x), f2b(x2.y), f2b(x2.z), f2b(x2.w),
             f2b(x3.x), f2b(x3.y), f2b(x3.z), f2b(x3.w)};

  size_t tb = (size_t)(n >> 6) * 8192;
  int nperm = (n & 3) | ((n & 16) >> 2);
  size_t vbase = tb + 4096 + ((n & 32) >> 5) * 2048 + ((n & 15) >> 2) * 128 + nperm;

#pragma unroll
  for (int i = 0; i < 4; ++i) {
    // A-frag: W[out-dim = i*16 + l15][k = quad*8 + j], direct from fp32
    const float* wr = W + (size_t)(i * 16 + l15) * DIM + quad * 8;
    float4 a0 = *(const float4*)&wr[0];
    float4 a1 = *(const float4*)&wr[4];
    float4 a2 = *(const float4*)&wr[32];
    float4 a3 = *(const float4*)&wr[36];
    s8v wf0 = {f2b(a0.x), f2b(a0.y), f2b(a0.z), f2b(a0.w),
               f2b(a1.x), f2b(a1.y), f2b(a1.z), f2b(a1.w)};
    s8v wf1 = {f2b(a2.x), f2b(a2.y), f2b(a2.z), f2b(a2.w),
               f2b(a3.x), f2b(a3.y), f2b(a3.z), f2b(a3.w)};
    f4v acc = (f4v){0.f, 0.f, 0.f, 0.f};
    acc = __builtin_amdgcn_mfma_f32_16x16x32_bf16(wf0, xf0, acc, 0, 0, 0);
    acc = __builtin_amdgcn_mfma_f32_16x16x32_bf16(wf1, xf1, acc, 0, 0, 0);
    // C[row = out-dim = i*16 + quad*4 + r][col = token = l15], group-local
    int d0 = i * 16 + quad * 4;
    float4 bias = *(const float4*)&Bb[d0];
    float4 th4 = *(const float4*)&theta[d0];
    float y0 = __cosf(acc[0] + bias.x) * __cosf(th4.x);
    float y1 = __cosf(acc[1] + bias.y) * __cosf(th4.y);
    float y2 = __cosf(acc[2] + bias.z) * __cosf(th4.z);
    float y3 = __cosf(acc[3] + bias.w) * __cosf(th4.w);
    if (mg == 0) {
      s4v p = {f2b(SC2 * y0), f2b(SC2 * y1), f2b(SC2 * y2), f2b(SC2 * y3)};
      *(s4v*)&qq[(size_t)n * DIM + d0] = p;
    } else if (mg == 1) {
      int e = d0;        // e&7 advances with r; higher fields constant over r
      size_t idx = tb + ((n & 63) >> 4) * 1024 + (e >> 5) * 512 +
                   ((e & 31) >> 3) * 128 + (n & 15) * 8 + (e & 7);
      s4v p = {f2b(y0), f2b(y1), f2b(y2), f2b(y3)};
      *(s4v*)&kvT[idx] = p;
    } else {
      float ys[4] = {y0, y1, y2, y3};
#pragma unroll
      for (int r = 0; r < 4; ++r) {
        int e = d0 + r;
        kvT[vbase + (e >> 4) * 512 + (e & 15) * 8] = f2b(ys[r]);
      }
    }
  }
}

// ---------------- Flash attention + fused last-block merge ------------------
// Flash main loop identical to round 6: single-wave blocks, zero barriers,
// wave-private LDS double buffer, counted s_waitcnt vmcnt(8) pipeline (T4),
// setprio around the pure-MFMA cluster (T5).
//
// MERGE FUSION: after storing its split's partials, each block does a
// device-scope release (__threadfence) + atomicAdd on cnt[qblock]. The 16th
// arriver acquires and merges its 64 query rows in-place: split-sum of
// pO/pL (coalesced, 16-deep MLP), rcp-normalize, then out = att @ wo^T + bo
// as 32 MFMAs with att staged in the re-used LDS (stride 68 floats = 2-way
// bank aliasing, free) and wo/bo read from fp32 global like qkv's A-frags.
// 127/128 merges overlap flash's tail; the merge kernel + launch disappear.
#if __has_builtin(__builtin_amdgcn_global_load_lds)
#define DMA_CHUNK(srcp, dstp) \
  __builtin_amdgcn_global_load_lds( \
      (const __attribute__((address_space(1))) void*)(srcp), \
      (__attribute__((address_space(3))) void*)(dstp), 16, 0, 0)
#else
#define DMA_CHUNK(srcp, dstp) \
  { *(s8v*)((short*)(dstp) + (threadIdx.x & 63) * 8) = \
        *(const s8v*)((const short*)(srcp)); }
#endif

__global__ __launch_bounds__(64, 2) void flash_kernel(
    const short* __restrict__ qq, const short* __restrict__ kvT,
    short* __restrict__ pO, short* __restrict__ pL,
    const float* __restrict__ wo, const float* __restrict__ bo,
    float* __restrict__ out, int* __restrict__ cnt) {
  // overlay: staging dbuf (2 x 4096 shorts = 16384 B) OR merge att
  // (64 x 68 x 4 = 17408 B) + ri (256 B)
  __shared__ __align__(16) char smem[17664];
  short* stage = (short*)smem;

  int lane = threadIdx.x & 63;
  int l15 = lane & 15, quad = lane >> 4;
  int qblock = blockIdx.x >> 4, split = blockIdx.x & 15;
  int qbase = qblock * FQB;

  // Q B-frags: B[n=query=l15][k=dim=quad*8+j], two k-halves, 4 q-subtiles
  s8v qf[4][2];
#pragma unroll
  for (int qt = 0; qt < 4; ++qt) {
    const short* qr = qq + (qbase + qt * 16 + l15) * DIM + quad * 8;
    qf[qt][0] = *(const s8v*)qr;
    qf[qt][1] = *(const s8v*)(qr + 32);
  }
  // retire qf loads so the vmcnt ledger below counts ONLY DMA chunks
  asm volatile("s_waitcnt vmcnt(0)" ::: "memory");

  const short ONE = (short)0x3F80;  // bf16 1.0
  const s8v ones = {ONE, ONE, ONE, ONE, ONE, ONE, ONE, ONE};

  f4v o[4][4], ol[4];
#pragma unroll
  for (int qt = 0; qt < 4; ++qt) {
    ol[qt] = (f4v){0.f, 0.f, 0.f, 0.f};
#pragma unroll
    for (int c = 0; c < 4; ++c) o[qt][c] = (f4v){0.f, 0.f, 0.f, 0.f};
  }

  // 32-key step S of this split: 64-key tile (S>>1), half S&1.
  const short* kvs = kvT + (size_t)(split * (KEYS_PER_SPLIT / 64)) * 8192 +
                     lane * 8;
#define STAGE32(S, BUF)                                                      \
  {                                                                          \
    const short* s_ = kvs + ((S) >> 1) * 8192 + ((S) & 1) * 2048;            \
    short* d_ = stage + (BUF) * 4096;                                        \
    _Pragma("unroll") for (int c2 = 0; c2 < 4; ++c2) {                       \
      DMA_CHUNK(s_ + c2 * 512, d_ + c2 * 512);                               \
      DMA_CHUNK(s_ + 4096 + c2 * 512, d_ + 2048 + c2 * 512);                 \
    }                                                                        \
  }

  STAGE32(0, 0)

  for (int s = 0; s < NSTEPS; ++s) {
    if (s + 1 < NSTEPS) {
      STAGE32(s + 1, (s + 1) & 1)
      // outstanding = 16 (step s + step s+1); wait for step s's 8 only
      asm volatile("s_waitcnt vmcnt(8)" ::: "memory");
    } else {
      asm volatile("s_waitcnt vmcnt(0)" ::: "memory");
    }
    __builtin_amdgcn_sched_barrier(0);

    const short* kb = stage + (s & 1) * 4096;
    const short* vb = kb + 2048;

    i4v pai[4];                      // exp'd P over these 32 keys, per qt
#pragma unroll
    for (int h = 0; h < 2; ++h) {    // 16-key sub-tile within the step
      s8v kf0 = *(const s8v*)&kb[(h * 2) * 512 + lane * 8];
      s8v kf1 = *(const s8v*)&kb[(h * 2 + 1) * 512 + lane * 8];
#pragma unroll
      for (int qt = 0; qt < 4; ++qt) {
        f4v acc = (f4v){0.f, 0.f, 0.f, 0.f};
        acc = __builtin_amdgcn_mfma_f32_16x16x32_bf16(kf0, qf[qt][0], acc, 0, 0, 0);
        acc = __builtin_amdgcn_mfma_f32_16x16x32_bf16(kf1, qf[qt][1], acc, 0, 0, 0);
        // acc[r] = SC2*S^T[key=h*16+quad*4+r][query=qt*16+l15]
        pai[qt][h * 2]     = pack_bf16x2(fast_exp2(acc[0]), fast_exp2(acc[1]));
        pai[qt][h * 2 + 1] = pack_bf16x2(fast_exp2(acc[2]), fast_exp2(acc[3]));
      }
    }
    // pure-MFMA cluster: row sums + PV (T5)
    __builtin_amdgcn_s_setprio(1);
#pragma unroll
    for (int qt = 0; qt < 4; ++qt)
      ol[qt] = __builtin_amdgcn_mfma_f32_16x16x32_bf16(
          __builtin_bit_cast(s8v, pai[qt]), ones, ol[qt], 0, 0, 0);
#pragma unroll
    for (int c = 0; c < 4; ++c) {
      s8v vf = *(const s8v*)&vb[c * 512 + lane * 8];
#pragma unroll
      for (int qt = 0; qt < 4; ++qt)
        o[qt][c] = __builtin_amdgcn_mfma_f32_16x16x32_bf16(
            __builtin_bit_cast(s8v, pai[qt]), vf, o[qt][c], 0, 0, 0);
    }
    __builtin_amdgcn_s_setprio(0);
  }

  // store bf16 partials: pO[split][q][e], pL[split][q]
#pragma unroll
  for (int qt = 0; qt < 4; ++qt) {
#pragma unroll
    for (int r = 0; r < 4; ++r) {
      int q = qbase + qt * 16 + quad * 4 + r;
      short* dst = pO + ((size_t)split * NQ + q) * DIM;
#pragma unroll
      for (int c = 0; c < 4; ++c) dst[c * 16 + l15] = f2b(o[qt][c][r]);
      if (l15 == 0) pL[(size_t)split * NQ + q] = f2b(ol[qt][r]);
    }
  }

  // ---- last-block merge for this qblock ----
  __threadfence();                       // release: pO/pL visible device-wide
  int old = 0;
  if (lane == 0) old = atomicAdd(&cnt[qblock], 1);
  old = __shfl(old, 0);
  if (old != SPLITS - 1) return;
  __threadfence();                       // acquire: see all splits' partials

  float* attf = (float*)smem;            // [64][ATTSTR]
  float* rif  = attf + 64 * ATTSTR;      // [64]

  // row sums -> reciprocal (lane owns row = lane)
  {
    const short* lp = pL + qbase + lane;
    float lsum = 0.f;
#pragma unroll
    for (int sp = 0; sp < SPLITS; ++sp) lsum += b2f(lp[(size_t)sp * NQ]);
    rif[lane] = fast_rcp(lsum);
  }
  // att split-sums: lane owns e-pair (lane&31), rows 2*r2 + (lane>>5)
  {
    int e2 = lane & 31, half = lane >> 5;
    const short* psrc = pO + ((size_t)(qbase + half)) * DIM + e2 * 2;
#pragma unroll 4
    for (int r2 = 0; r2 < 32; ++r2) {
      int row = r2 * 2 + half;
      const short* pr = psrc + (size_t)r2 * 2 * DIM;
      float a0 = 0.f, a1 = 0.f;
#pragma unroll
      for (int sp = 0; sp < SPLITS; ++sp) {
        unsigned int u = *(const unsigned int*)&pr[(size_t)sp * NQ * DIM];
        a0 += b2f_lo(u);
        a1 += b2f_hi(u);
      }
      *(float2*)&attf[row * ATTSTR + e2 * 2] = make_float2(a0, a1);
    }
  }
  // (single wave: compiler inserts lgkmcnt before dependent ds_reads)

  // B-frags from wo (hoisted): B[n = d = ct*16+l15][k = h*32 + quad*8 + j]
  s8v bf[4][2];
  float bov[4];
#pragma unroll
  for (int ct = 0; ct < 4; ++ct) {
    const float* wr = wo + (size_t)(ct * 16 + l15) * DIM + quad * 8;
    float4 c0 = *(const float4*)&wr[0];
    float4 c1 = *(const float4*)&wr[4];
    float4 c2 = *(const float4*)&wr[32];
    float4 c3 = *(const float4*)&wr[36];
    bf[ct][0] = {f2b(c0.x), f2b(c0.y), f2b(c0.z), f2b(c0.w),
                 f2b(c1.x), f2b(c1.y), f2b(c1.z), f2b(c1.w)};
    bf[ct][1] = {f2b(c2.x), f2b(c2.y), f2b(c2.z), f2b(c2.w),
                 f2b(c3.x), f2b(c3.y), f2b(c3.z), f2b(c3.w)};
    bov[ct] = bo[ct * 16 + l15];
  }
#pragma unroll
  for (int rt = 0; rt < 4; ++rt) {
    int row = rt * 16 + l15;
    float riv = rif[row];
    const float* ar = &attf[row * ATTSTR + quad * 8];
    s8v af0 = {f2b(ar[0] * riv), f2b(ar[1] * riv), f2b(ar[2] * riv),
               f2b(ar[3] * riv), f2b(ar[4] * riv), f2b(ar[5] * riv),
               f2b(ar[6] * riv), f2b(ar[7] * riv)};
    s8v af1 = {f2b(ar[32] * riv), f2b(ar[33] * riv), f2b(ar[34] * riv),
               f2b(ar[35] * riv), f2b(ar[36] * riv), f2b(ar[37] * riv),
               f2b(ar[38] * riv), f2b(ar[39] * riv)};
#pragma unroll
    for (int ct = 0; ct < 4; ++ct) {
      f4v acc = (f4v){0.f, 0.f, 0.f, 0.f};
      acc = __builtin_amdgcn_mfma_f32_16x16x32_bf16(af0, bf[ct][0], acc, 0, 0, 0);
      acc = __builtin_amdgcn_mfma_f32_16x16x32_bf16(af1, bf[ct][1], acc, 0, 0, 0);
      // C[row = q = rt*16 + quad*4 + r][col = d = ct*16 + l15]
#pragma unroll
      for (int r = 0; r < 4; ++r)
        out[(size_t)(qbase + rt * 16 + quad * 4 + r) * DIM + ct * 16 + l15] =
            acc[r] + bov[ct];
    }
  }
}

extern "C" void kernel_launch(void* const* d_in, const int* in_sizes, int n_in,
                              void* d_out, int out_size, void* d_ws, size_t ws_size,
                              hipStream_t stream) {
  const float* x  = (const float*)d_in[0];
  const float* wq = (const float*)d_in[1];
  const float* bq = (const float*)d_in[2];
  const float* wk = (const float*)d_in[3];
  const float* bk = (const float*)d_in[4];
  const float* wv = (const float*)d_in[5];
  const float* bv = (const float*)d_in[6];
  const float* th = (const float*)d_in[7];
  const float* wo = (const float*)d_in[8];
  const float* bo = (const float*)d_in[9];

  char* ws = (char*)d_ws;
  short* qq  = (short*)(ws);                            // 1 MB  (Q, row-major, SC2-scaled)
  short* kvT = (short*)(ws + (1u << 20));               // 2 MB  (K+V frag-tiled)
  short* pO  = (short*)(ws + (3u << 20));               // 16 MB bf16 partials [sp][q][e]
  short* pL  = (short*)(ws + (19u << 20));              // 256 KB bf16 sums [sp][q]
  int*   cnt = (int*)(ws + (19u << 20) + (256u << 10)); // 512 B merge counters

  hipLaunchKernelGGL(qkv_kernel, dim3(NQ / 16, 3), dim3(64), 0, stream,
                     x, wq, bq, wk, bk, wv, bv, th, qq, kvT, cnt);
  hipLaunchKernelGGL(flash_kernel, dim3(GRID_FLASH), dim3(FQB), 0, stream,
                     qq, kvT, pO, pL, wo, bo, (float*)d_out, cnt);
}

// Round 8
// 114.223 us; speedup vs baseline: 2.3557x; 2.3557x over previous
//
#include <hip/hip_runtime.h>
#include <hip/hip_bf16.h>

// Problem constants
#define NQ 8192            // B*S flattened tokens
#define DIM 64             // embed dim
#define SPLITS 16          // key-dimension split (partials merged by kernel 3)
#define FQB 64             // queries per flash block = ONE wave
#define KEYS_PER_SPLIT (NQ / SPLITS)       // 512
#define NSTEPS (KEYS_PER_SPLIT / 32)       // 16 x 32-key steps
#define GRID_FLASH ((NQ / FQB) * SPLITS)   // 2048
#define MERGEB 1024        // merge grid (4 blocks/CU)
#define MROWS (NQ / MERGEB)                // 8 rows per merge block
#define SC2 0.51012301920911057f           // (1/sqrt(8)) * log2(e), folded into qq
#define KSTR 72            // LDS row stride in shorts (merge weight tile)

typedef short s8v __attribute__((ext_vector_type(8)));   // 8 x bf16 bits
typedef short s4v __attribute__((ext_vector_type(4)));   // 4 x bf16 bits
typedef float f4v __attribute__((ext_vector_type(4)));
typedef int   i4v __attribute__((ext_vector_type(4)));

__device__ __forceinline__ float b2f(short s) {
  unsigned int u = ((unsigned int)(unsigned short)s) << 16;
  return __uint_as_float(u);
}
__device__ __forceinline__ float b2f_lo(unsigned int u) {
  return __uint_as_float(u << 16);
}
__device__ __forceinline__ float b2f_hi(unsigned int u) {
  return __uint_as_float(u & 0xffff0000u);
}
__device__ __forceinline__ short f2b(float f) {
  __hip_bfloat16 h = __float2bfloat16(f);
  return *reinterpret_cast<short*>(&h);
}
__device__ __forceinline__ int pack_bf16x2(float a, float b) {
  union { __hip_bfloat162 h; int i; } u;
  u.h = __float22bfloat162_rn(make_float2(a, b));
  return u.i;
}
__device__ __forceinline__ float fast_exp2(float x) {
#if __has_builtin(__builtin_amdgcn_exp2f)
  return __builtin_amdgcn_exp2f(x);   // single v_exp_f32, no OCML call
#else
  return exp2f(x);
#endif
}

// ---------------- QKV projection + quantum map (fp32 in, bf16 out) ----------
// One wave per block, grid (512 token-groups x 3 mt-groups) = 1536 blocks
// (6 blocks/CU, free-running: no LDS, no barriers, NO prep kernel). Each wave
// reads its W MFMA fragments DIRECTLY from the fp32 weight matrix (2 float4
// per fragment half; 16 KB per matrix -> L2-resident after first touch) and
// converts in-register. 8 MFMAs + cos epilogue on C fragments.
// kvT is FRAGMENT-LINEAR TILED (8192 shorts per 64-key tile: 8 K-chunks then
// 8 V-chunks of 512 = chunk*512 + lane*8 + j), so flash stages sub-tiles with
// linear conflict-free DMA and reads fragments with zero repack. V chunks
// bake in the K=32 PV key permutation.
__global__ __launch_bounds__(64) void qkv_kernel(
    const float* __restrict__ x,
    const float* __restrict__ wq, const float* __restrict__ bq,
    const float* __restrict__ wk, const float* __restrict__ bk,
    const float* __restrict__ wv, const float* __restrict__ bv,
    const float* __restrict__ theta,
    short* __restrict__ qq, short* __restrict__ kvT) {
  int lane = threadIdx.x & 63;
  int l15 = lane & 15, quad = lane >> 4;
  int tg = blockIdx.x;     // token group (16 tokens)
  int mg = blockIdx.y;     // 0 = Q, 1 = K, 2 = V
  int n = tg * 16 + l15;   // this lane's token (as C column)

  const float* W  = (mg == 0) ? wq : (mg == 1) ? wk : wv;
  const float* Bb = (mg == 0) ? bq : (mg == 1) ? bk : bv;

  // B-frag: X[token = l15][k = quad*8 + j], two k-halves (fp32 -> bf16)
  const float* xr = x + (size_t)n * DIM + quad * 8;
  float4 x0 = *(const float4*)&xr[0];
  float4 x1 = *(const float4*)&xr[4];
  float4 x2 = *(const float4*)&xr[32];
  float4 x3 = *(const float4*)&xr[36];
  s8v xf0 = {f2b(x0.x), f2b(x0.y), f2b(x0.z), f2b(x0.w),
             f2b(x1.x), f2b(x1.y), f2b(x1.z), f2b(x1.w)};
  s8v xf1 = {f2b(x2.x), f2b(x2.y), f2b(x2.z), f2b(x2.w),
             f2b(x3.x), f2b(x3.y), f2b(x3.z), f2b(x3.w)};

  size_t tb = (size_t)(n >> 6) * 8192;
  int nperm = (n & 3) | ((n & 16) >> 2);
  size_t vbase = tb + 4096 + ((n & 32) >> 5) * 2048 + ((n & 15) >> 2) * 128 + nperm;

#pragma unroll
  for (int i = 0; i < 4; ++i) {
    // A-frag: W[out-dim = i*16 + l15][k = quad*8 + j], direct from fp32
    const float* wr = W + (size_t)(i * 16 + l15) * DIM + quad * 8;
    float4 a0 = *(const float4*)&wr[0];
    float4 a1 = *(const float4*)&wr[4];
    float4 a2 = *(const float4*)&wr[32];
    float4 a3 = *(const float4*)&wr[36];
    s8v wf0 = {f2b(a0.x), f2b(a0.y), f2b(a0.z), f2b(a0.w),
               f2b(a1.x), f2b(a1.y), f2b(a1.z), f2b(a1.w)};
    s8v wf1 = {f2b(a2.x), f2b(a2.y), f2b(a2.z), f2b(a2.w),
               f2b(a3.x), f2b(a3.y), f2b(a3.z), f2b(a3.w)};
    f4v acc = (f4v){0.f, 0.f, 0.f, 0.f};
    acc = __builtin_amdgcn_mfma_f32_16x16x32_bf16(wf0, xf0, acc, 0, 0, 0);
    acc = __builtin_amdgcn_mfma_f32_16x16x32_bf16(wf1, xf1, acc, 0, 0, 0);
    // C[row = out-dim = i*16 + quad*4 + r][col = token = l15], group-local
    int d0 = i * 16 + quad * 4;
    float4 bias = *(const float4*)&Bb[d0];
    float4 th4 = *(const float4*)&theta[d0];
    float y0 = __cosf(acc[0] + bias.x) * __cosf(th4.x);
    float y1 = __cosf(acc[1] + bias.y) * __cosf(th4.y);
    float y2 = __cosf(acc[2] + bias.z) * __cosf(th4.z);
    float y3 = __cosf(acc[3] + bias.w) * __cosf(th4.w);
    if (mg == 0) {
      s4v p = {f2b(SC2 * y0), f2b(SC2 * y1), f2b(SC2 * y2), f2b(SC2 * y3)};
      *(s4v*)&qq[(size_t)n * DIM + d0] = p;
    } else if (mg == 1) {
      int e = d0;        // e&7 advances with r; higher fields constant over r
      size_t idx = tb + ((n & 63) >> 4) * 1024 + (e >> 5) * 512 +
                   ((e & 31) >> 3) * 128 + (n & 15) * 8 + (e & 7);
      s4v p = {f2b(y0), f2b(y1), f2b(y2), f2b(y3)};
      *(s4v*)&kvT[idx] = p;
    } else {
      float ys[4] = {y0, y1, y2, y3};
#pragma unroll
      for (int r = 0; r < 4; ++r) {
        int e = d0 + r;
        kvT[vbase + (e >> 4) * 512 + (e & 15) * 8] = f2b(ys[r]);
      }
    }
  }
}

// ---------------- Flash attention (no-max streaming softmax) ----------------
// |s| <= 64/sqrt(8) = 22.6 -> exp(s) <= 6.6e9, row sums <= 5.5e13: fp32-safe,
// so no running max; split partials merge by pure summation.
// QK computed as S^T (A=K, B=Q): exp'd C-regs are directly a PV A-operand.
// PV uses K=32 MFMA with the key-perm baked into kvT's V chunks.
// Row sums l computed by an extra MFMA against an all-ones B fragment.
//
// SINGLE-WAVE BLOCKS, ZERO BARRIERS: each wave stages its own 32-key step
// (8 KB: 4 K chunks + 4 V chunks) into a wave-private LDS double buffer via
// global_load_lds, pipelined with COUNTED s_waitcnt vmcnt(8) (T4: step s+1's
// 8 chunks stay in flight while step s computes; never drain to 0 in-loop).
// vmcnt is wave-local so no cross-wave hazard exists; qf loads are drained
// once up front so the vmcnt ledger counts DMA chunks only. 16 KB LDS/block
// -> 8 one-wave blocks/CU co-resident (grid 2048), all free-running.
// NOTE (round 7 lesson): do NOT fuse the merge here via __threadfence —
// device-scope fences on non-coherent per-XCD L2s cost ~20x (flash 203 us,
// HBM 2%). The kernel boundary is the cheap device-scope release.
#if __has_builtin(__builtin_amdgcn_global_load_lds)
#define DMA_CHUNK(srcp, dstp) \
  __builtin_amdgcn_global_load_lds( \
      (const __attribute__((address_space(1))) void*)(srcp), \
      (__attribute__((address_space(3))) void*)(dstp), 16, 0, 0)
#else
#define DMA_CHUNK(srcp, dstp) \
  { *(s8v*)((short*)(dstp) + (threadIdx.x & 63) * 8) = \
        *(const s8v*)((const short*)(srcp)); }
#endif

__global__ __launch_bounds__(64, 2) void flash_kernel(
    const short* __restrict__ qq, const short* __restrict__ kvT,
    short* __restrict__ pO, short* __restrict__ pL) {
  __shared__ __align__(16) short lds[2][4096];  // dbuf: 4 K + 4 V chunks each

  int lane = threadIdx.x & 63;
  int l15 = lane & 15, quad = lane >> 4;
  int qblock = blockIdx.x >> 4, split = blockIdx.x & 15;
  int qbase = qblock * FQB;

  // Q B-frags: B[n=query=l15][k=dim=quad*8+j], two k-halves, 4 q-subtiles
  s8v qf[4][2];
#pragma unroll
  for (int qt = 0; qt < 4; ++qt) {
    const short* qr = qq + (qbase + qt * 16 + l15) * DIM + quad * 8;
    qf[qt][0] = *(const s8v*)qr;
    qf[qt][1] = *(const s8v*)(qr + 32);
  }
  // retire qf loads so the vmcnt ledger below counts ONLY DMA chunks
  asm volatile("s_waitcnt vmcnt(0)" ::: "memory");

  const short ONE = (short)0x3F80;  // bf16 1.0
  const s8v ones = {ONE, ONE, ONE, ONE, ONE, ONE, ONE, ONE};

  f4v o[4][4], ol[4];
#pragma unroll
  for (int qt = 0; qt < 4; ++qt) {
    ol[qt] = (f4v){0.f, 0.f, 0.f, 0.f};
#pragma unroll
    for (int c = 0; c < 4; ++c) o[qt][c] = (f4v){0.f, 0.f, 0.f, 0.f};
  }

  // 32-key step S of this split: 64-key tile gt0 + (S>>1), half S&1.
  // K chunks [4*(S&1)..+3] at tile base; V chunks same indices at +4096.
  const short* kvs = kvT + (size_t)(split * (KEYS_PER_SPLIT / 64)) * 8192 +
                     lane * 8;
#define STAGE32(S, BUF)                                                      \
  {                                                                          \
    const short* s_ = kvs + ((S) >> 1) * 8192 + ((S) & 1) * 2048;            \
    short* d_ = &lds[BUF][0];                                                \
    _Pragma("unroll") for (int c2 = 0; c2 < 4; ++c2) {                       \
      DMA_CHUNK(s_ + c2 * 512, d_ + c2 * 512);                               \
      DMA_CHUNK(s_ + 4096 + c2 * 512, d_ + 2048 + c2 * 512);                 \
    }                                                                        \
  }

  STAGE32(0, 0)

  for (int s = 0; s < NSTEPS; ++s) {
    if (s + 1 < NSTEPS) {
      STAGE32(s + 1, (s + 1) & 1)
      // outstanding = 16 (step s + step s+1); wait for step s's 8 only
      asm volatile("s_waitcnt vmcnt(8)" ::: "memory");
    } else {
      asm volatile("s_waitcnt vmcnt(0)" ::: "memory");
    }
    __builtin_amdgcn_sched_barrier(0);

    const short* kb = lds[s & 1];
    const short* vb = kb + 2048;

    i4v pai[4];                      // exp'd P over these 32 keys, per qt
#pragma unroll
    for (int h = 0; h < 2; ++h) {    // 16-key sub-tile within the step
      s8v kf0 = *(const s8v*)&kb[(h * 2) * 512 + lane * 8];
      s8v kf1 = *(const s8v*)&kb[(h * 2 + 1) * 512 + lane * 8];
#pragma unroll
      for (int qt = 0; qt < 4; ++qt) {
        f4v acc = (f4v){0.f, 0.f, 0.f, 0.f};
        acc = __builtin_amdgcn_mfma_f32_16x16x32_bf16(kf0, qf[qt][0], acc, 0, 0, 0);
        acc = __builtin_amdgcn_mfma_f32_16x16x32_bf16(kf1, qf[qt][1], acc, 0, 0, 0);
        // acc[r] = SC2*S^T[key=h*16+quad*4+r][query=qt*16+l15]
        pai[qt][h * 2]     = pack_bf16x2(fast_exp2(acc[0]), fast_exp2(acc[1]));
        pai[qt][h * 2 + 1] = pack_bf16x2(fast_exp2(acc[2]), fast_exp2(acc[3]));
      }
    }
    // pure-MFMA cluster: row sums + PV (T5)
    __builtin_amdgcn_s_setprio(1);
#pragma unroll
    for (int qt = 0; qt < 4; ++qt)
      ol[qt] = __builtin_amdgcn_mfma_f32_16x16x32_bf16(
          __builtin_bit_cast(s8v, pai[qt]), ones, ol[qt], 0, 0, 0);
#pragma unroll
    for (int c = 0; c < 4; ++c) {
      s8v vf = *(const s8v*)&vb[c * 512 + lane * 8];
#pragma unroll
      for (int qt = 0; qt < 4; ++qt)
        o[qt][c] = __builtin_amdgcn_mfma_f32_16x16x32_bf16(
            __builtin_bit_cast(s8v, pai[qt]), vf, o[qt][c], 0, 0, 0);
    }
    __builtin_amdgcn_s_setprio(0);
  }

  // store bf16 partials: pO[split][q][e] (merge reads per-lane over sp, no
  // shuffles), pL[split][q]
#pragma unroll
  for (int qt = 0; qt < 4; ++qt) {
#pragma unroll
    for (int r = 0; r < 4; ++r) {
      int q = qbase + qt * 16 + quad * 4 + r;
      short* dst = pO + ((size_t)split * NQ + q) * DIM;
#pragma unroll
      for (int c = 0; c < 4; ++c) dst[c * 16 + l15] = f2b(o[qt][c][r]);
      if (l15 == 0) pL[(size_t)split * NQ + q] = f2b(ol[qt][r]);
    }
  }
}

// ---------------- merge partials + output projection (fp32 out) -------------
// pO[sp][q][e]: the split-sum is a per-lane serial loop of 16 coalesced dword
// loads (16-deep MLP, no shuffles, no idle lanes). Grid 1024 = 4 blocks/CU.
__global__ __launch_bounds__(256) void merge_kernel(
    const short* __restrict__ pO, const short* __restrict__ pL,
    const float* __restrict__ wo, const float* __restrict__ bo,
    float* __restrict__ out) {
  __shared__ __align__(16) short wsh[DIM * KSTR];
  __shared__ __align__(16) float att[MROWS * DIM];
  int tid = threadIdx.x;
  int q0 = blockIdx.x * MROWS;
  for (int i = tid; i < DIM * 16; i += 256) {
    int r = i >> 4, c4 = (i & 15) << 2;
    float4 w = *(const float4*)&wo[r * DIM + c4];
    s4v p = {f2b(w.x), f2b(w.y), f2b(w.z), f2b(w.w)};
    *(s4v*)&wsh[r * KSTR + c4] = p;
  }
  // phase 1: thread owns (row = tid>>5, e-pair = (tid&31)*2); 8 rows x 64 e
  {
    int e2 = (tid & 31) * 2, rg8 = tid >> 5;
    int q = q0 + rg8;
    const short* psrc = pO + (size_t)q * DIM + e2;
    const short* lsrc = pL + q;
    float a0 = 0.f, a1 = 0.f, l = 0.f;
#pragma unroll
    for (int sp = 0; sp < SPLITS; ++sp) {
      unsigned int u = *(const unsigned int*)&psrc[(size_t)sp * NQ * DIM];
      a0 += b2f_lo(u);
      a1 += b2f_hi(u);
      l += b2f(lsrc[(size_t)sp * NQ]);
    }
#if __has_builtin(__builtin_amdgcn_rcpf)
    float ri = __builtin_amdgcn_rcpf(l);
#else
    float ri = 1.f / l;
#endif
    att[rg8 * DIM + e2] = a0 * ri;
    att[rg8 * DIM + e2 + 1] = a1 * ri;
  }
  __syncthreads();
  // phase 2: out = att @ wo^T + bo
  int e = tid & 63, rg = tid >> 6;
  for (int rr = rg; rr < MROWS; rr += 4) {
    float acc = bo[e];
#pragma unroll
    for (int c8 = 0; c8 < 8; ++c8) {
      s8v w = *(const s8v*)&wsh[e * KSTR + c8 * 8];
      const float* ar = &att[rr * DIM + c8 * 8];
      acc += ar[0] * b2f(w[0]) + ar[1] * b2f(w[1]) + ar[2] * b2f(w[2]) + ar[3] * b2f(w[3])
           + ar[4] * b2f(w[4]) + ar[5] * b2f(w[5]) + ar[6] * b2f(w[6]) + ar[7] * b2f(w[7]);
    }
    out[(size_t)(q0 + rr) * DIM + e] = acc;
  }
}

extern "C" void kernel_launch(void* const* d_in, const int* in_sizes, int n_in,
                              void* d_out, int out_size, void* d_ws, size_t ws_size,
                              hipStream_t stream) {
  const float* x  = (const float*)d_in[0];
  const float* wq = (const float*)d_in[1];
  const float* bq = (const float*)d_in[2];
  const float* wk = (const float*)d_in[3];
  const float* bk = (const float*)d_in[4];
  const float* wv = (const float*)d_in[5];
  const float* bv = (const float*)d_in[6];
  const float* th = (const float*)d_in[7];
  const float* wo = (const float*)d_in[8];
  const float* bo = (const float*)d_in[9];

  char* ws = (char*)d_ws;
  short* qq  = (short*)(ws);                            // 1 MB  (Q, row-major, SC2-scaled)
  short* kvT = (short*)(ws + (1u << 20));               // 2 MB  (K+V frag-tiled)
  short* pO  = (short*)(ws + (3u << 20));               // 16 MB bf16 partials [sp][q][e]
  short* pL  = (short*)(ws + (19u << 20));              // 256 KB bf16 sums [sp][q]

  hipLaunchKernelGGL(qkv_kernel, dim3(NQ / 16, 3), dim3(64), 0, stream,
                     x, wq, bq, wk, bk, wv, bv, th, qq, kvT);
  hipLaunchKernelGGL(flash_kernel, dim3(GRID_FLASH), dim3(FQB), 0, stream,
                     qq, kvT, pO, pL);
  hipLaunchKernelGGL(merge_kernel, dim3(MERGEB), dim3(256), 0, stream,
                     pO, pL, wo, bo, (float*)d_out);
}